// Round 1
// 1115.995 us; speedup vs baseline: 1.1513x; 1.1513x over previous
//
#include <hip/hip_runtime.h>
#include <stdint.h>

typedef float f32x4 __attribute__((ext_vector_type(4)));
typedef short bf16x8 __attribute__((ext_vector_type(8)));

#define BM 128
#define BN 128
#define BK 32
#define LDA 40   // fallback path LDS stride

#if defined(__has_builtin)
#  if __has_builtin(__builtin_amdgcn_global_load_lds)
#    define HAVE_GLLDS 1
#  endif
#endif
#ifndef HAVE_GLLDS
#  define HAVE_GLLDS 0
#endif

__device__ __forceinline__ uint32_t pack_bf16(float a, float b) {
  // round-half-up truncation to bf16, packed (a->low16, b->high16)
  uint32_t ua = __builtin_bit_cast(uint32_t, a);
  uint32_t ub = __builtin_bit_cast(uint32_t, b);
  ua += 0x8000u;
  ub += 0x8000u;
  return (ua >> 16) | (ub & 0xffff0000u);
}

#if HAVE_GLLDS
__device__ __forceinline__ void gload_lds16(const void* g, void* l) {
  // 16B per lane; LDS dest is wave-uniform base + lane*16 (linear layout required)
  __builtin_amdgcn_global_load_lds(
      (__attribute__((address_space(1))) void*)(uintptr_t)g,
      (__attribute__((address_space(3))) void*)(uint32_t)(uintptr_t)l,
      16, 0, 0);
}
#endif

// ---------------- conversion pre-passes (memory-bound) ----------------

// fp32 -> bf16 elementwise, 8 elems (32B read / 16B write) per thread-iter
__global__ __launch_bounds__(256)
void cvt_f32_bf16(const float* __restrict__ src, unsigned short* __restrict__ dst, long n8) {
  long i = (long)blockIdx.x * blockDim.x + threadIdx.x;
  const long stride = (long)gridDim.x * blockDim.x;
  for (; i < n8; i += stride) {
    const float4* p = (const float4*)(src + i * 8);
    float4 a = p[0], b = p[1];
    uint4 o;
    o.x = pack_bf16(a.x, a.y); o.y = pack_bf16(a.z, a.w);
    o.z = pack_bf16(b.x, b.y); o.w = pack_bf16(b.z, b.w);
    *(uint4*)(dst + i * 8) = o;
  }
}

// (E,K,N) fp32 -> (E,N,K) bf16 transposed (k-contiguous for global_load_lds)
// tile 64(k) x 32(n), block 256 = (32,8)
__global__ __launch_bounds__(256)
void tcvt(const float* __restrict__ src, unsigned short* __restrict__ dst,
          int K, int N, long sS, long sD) {
  __shared__ float tile[64][33];
  const int e = blockIdx.z;
  const float* S = src + (long)e * sS;
  unsigned short* Dp = dst + (long)e * sD;
  const int k0 = blockIdx.y * 64;
  const int n0 = blockIdx.x * 32;
  const int tx = threadIdx.x & 31;
  const int ty = threadIdx.x >> 5;
#pragma unroll
  for (int i = 0; i < 64; i += 8)
    tile[ty + i][tx] = S[(long)(k0 + ty + i) * N + (n0 + tx)];
  __syncthreads();
#pragma unroll
  for (int ii = 0; ii < 4; ii++) {
    const int n = ty + 8 * ii;
    const uint32_t w = pack_bf16(tile[2 * tx][n], tile[2 * tx + 1][n]);
    *(uint32_t*)&Dp[(long)(n0 + n) * K + k0 + 2 * tx] = w;  // 4B/lane, coalesced in k
  }
}

// ---------------- pure-bf16 GEMM, m97 structure ----------------
// A: (M,K) bf16 k-contig. B: (N,K) bf16 k-contig (pre-transposed weights).
// 128x128 tile, BK=32, 4 waves 2x2, global_load_lds 16B staging, linear LDS.
template<bool SWIGLU>
__global__ __launch_bounds__(256)
void gemm_bf16(const unsigned short* __restrict__ A,
               const unsigned short* __restrict__ B,
               const float* __restrict__ biasall,
               void* __restrict__ Outall,
               int M, int N, int K,
               long sA, long sB, long sBias, long sOut)
{
  __shared__ __align__(16) unsigned short As[BM * BK];  // [m][k], 8 KiB, linear
  __shared__ __align__(16) unsigned short Bs[BN * BK];  // [n][k], 8 KiB, linear

  const int e    = blockIdx.z;
  const int m0   = blockIdx.y * BM;
  const int n0   = blockIdx.x * BN;
  const int tid  = threadIdx.x;
  const int lane = tid & 63;
  const int wave = tid >> 6;
  const int q    = lane >> 4;      // quad 0..3
  const int c    = lane & 15;      // col-in-tile 0..15
  const int wm   = (wave >> 1) * 64;
  const int wn   = (wave & 1) * 64;

  // staging: wave w, issue s covers rows [s*64 + w*16, +16); lane -> (row, 16B k-chunk)
  const int stRow = wave * 16 + (lane >> 2);   // 0..63
  const int stK   = (lane & 3) * 8;            // k elem offset (8 bf16 = 16B)
  const unsigned short* gA = A + e * sA + (long)(m0 + stRow) * K + stK;
  const unsigned short* gB = B + e * sB + (long)(n0 + stRow) * K + stK;
  const long rowK64 = 64L * K;

  char* lA = (char*)As + wave * 1024;          // wave-uniform LDS base
  char* lB = (char*)Bs + wave * 1024;
#if !HAVE_GLLDS
  char* lAp = (char*)As + wave * 1024 + lane * 16;
  char* lBp = (char*)Bs + wave * 1024 + lane * 16;
#endif

  f32x4 acc[4][4];
#pragma unroll
  for (int i = 0; i < 4; i++)
#pragma unroll
    for (int j = 0; j < 4; j++)
      acc[i][j] = (f32x4){0.f, 0.f, 0.f, 0.f};

  for (int k0 = 0; k0 < K; k0 += BK) {
    if (k0) __syncthreads();   // previous iteration's fragment reads done
#if HAVE_GLLDS
    gload_lds16(gA + k0,          lA);
    gload_lds16(gA + k0 + rowK64, lA + 4096);
    gload_lds16(gB + k0,          lB);
    gload_lds16(gB + k0 + rowK64, lB + 4096);
#else
    {
      uint4 ra0 = *(const uint4*)(gA + k0);
      uint4 ra1 = *(const uint4*)(gA + k0 + rowK64);
      uint4 rb0 = *(const uint4*)(gB + k0);
      uint4 rb1 = *(const uint4*)(gB + k0 + rowK64);
      *(uint4*)lAp = ra0; *(uint4*)(lAp + 4096) = ra1;
      *(uint4*)lBp = rb0; *(uint4*)(lBp + 4096) = rb1;
    }
#endif
    __syncthreads();           // drains vmcnt(0): LDS tiles complete

    bf16x8 af[4], bfr[4];
#pragma unroll
    for (int i = 0; i < 4; i++)
      af[i] = *(const bf16x8*)&As[(wm + i * 16 + c) * BK + q * 8];
#pragma unroll
    for (int j = 0; j < 4; j++)
      bfr[j] = *(const bf16x8*)&Bs[(wn + j * 16 + c) * BK + q * 8];
#pragma unroll
    for (int i = 0; i < 4; i++)
#pragma unroll
      for (int j = 0; j < 4; j++)
        acc[i][j] = __builtin_amdgcn_mfma_f32_16x16x32_bf16(af[i], bfr[j], acc[i][j], 0, 0, 0);
  }

  // ---- epilogue (verified mapping: row = wm+i*16+q*4+r, col = wn+j*16+c) ----
  if (SWIGLU) {
    unsigned short* H = (unsigned short*)Outall + e * sOut;
    const int ldh = N >> 1;
#pragma unroll
    for (int j = 0; j < 4; j++) {
      const int f = n0 + wn + j * 16 + c;
      const float bias = biasall[e * sBias + f];
#pragma unroll
      for (int i = 0; i < 4; i++) {
        const int rb = m0 + wm + i * 16 + q * 4;
#pragma unroll
        for (int r = 0; r < 4; r++) {
          float v = acc[i][j][r] + bias;
          float p = __shfl_xor(v, 1);       // partner column (f^1), same row
          float xg = (f & 1) ? p : v;
          float xl = (f & 1) ? v : p;
          xg = fminf(xg, 7.f);
          xl = fminf(fmaxf(xl, -7.f), 7.f);
          float sig = 1.f / (1.f + __expf(-1.702f * xg));
          float res = xg * sig * (xl + 1.f);
          if ((f & 1) == 0) {
            uint32_t ub = __builtin_bit_cast(uint32_t, res) + 0x8000u;
            H[(long)(rb + r) * ldh + (f >> 1)] = (unsigned short)(ub >> 16);
          }
        }
      }
    }
  } else {
    float* O = (float*)Outall + e * sOut;
#pragma unroll
    for (int j = 0; j < 4; j++) {
      const int col = n0 + wn + j * 16 + c;
      const float bias = biasall[e * sBias + col];
#pragma unroll
      for (int i = 0; i < 4; i++) {
        const int rb = m0 + wm + i * 16 + q * 4;
#pragma unroll
        for (int r = 0; r < 4; r++)
          O[(long)(rb + r) * N + col] = acc[i][j][r] + bias;
      }
    }
  }
}

// ---------------- fallback: previous verified fused kernel ----------------
template<bool A_BF16, bool SWIGLU>
__global__ __launch_bounds__(256)
void gemm_fused(const void* __restrict__ Aall,
                const float* __restrict__ Ball,
                const float* __restrict__ biasall,
                void* __restrict__ Outall,
                int M, int N, int K,
                long sA, long sB, long sBias, long sOut)
{
  __shared__ __align__(16) unsigned short As[BM * LDA];
  __shared__ __align__(16) unsigned short Bs[BN * LDA];

  const int e    = blockIdx.z;
  const int m0   = blockIdx.y * BM;
  const int n0   = blockIdx.x * BN;
  const int tid  = threadIdx.x;
  const int lane = tid & 63;
  const int q    = lane >> 4;
  const int c    = lane & 15;
  const int wave = tid >> 6;
  const int wm   = (wave >> 1) * 64;
  const int wn   = (wave & 1) * 64;

  const int ar = tid >> 1;
  const int ah = (tid & 1) * 16;
  const int bkg = (tid >> 5) * 4;
  const int bng = tid & 31;

  const float* Bbase = Ball + e * sB + (long)bkg * N + (n0 + bng);

  const float*          A32 = nullptr;
  const unsigned short* A16 = nullptr;
  if (A_BF16) A16 = (const unsigned short*)Aall + e * sA + (long)(m0 + ar) * K + ah;
  else        A32 = (const float*)Aall          + e * sA + (long)(m0 + ar) * K + ah;

  f32x4 acc[4][4];
#pragma unroll
  for (int i = 0; i < 4; i++)
#pragma unroll
    for (int j = 0; j < 4; j++)
      acc[i][j] = (f32x4){0.f, 0.f, 0.f, 0.f};

  for (int k0 = 0; k0 < K; k0 += BK) {
    __syncthreads();
    uint32_t ad[8];
    if (A_BF16) {
      const uint4* p = (const uint4*)(A16 + k0);
      uint4 u0 = p[0], u1 = p[1];
      ad[0] = u0.x; ad[1] = u0.y; ad[2] = u0.z; ad[3] = u0.w;
      ad[4] = u1.x; ad[5] = u1.y; ad[6] = u1.z; ad[7] = u1.w;
    } else {
      const float4* p = (const float4*)(A32 + k0);
      float4 f0 = p[0], f1 = p[1], f2 = p[2], f3 = p[3];
      ad[0] = pack_bf16(f0.x, f0.y); ad[1] = pack_bf16(f0.z, f0.w);
      ad[2] = pack_bf16(f1.x, f1.y); ad[3] = pack_bf16(f1.z, f1.w);
      ad[4] = pack_bf16(f2.x, f2.y); ad[5] = pack_bf16(f2.z, f2.w);
      ad[6] = pack_bf16(f3.x, f3.y); ad[7] = pack_bf16(f3.z, f3.w);
    }
    {
      uint4* dstA = (uint4*)&As[ar * LDA + ah];
      dstA[0] = make_uint4(ad[0], ad[1], ad[2], ad[3]);
      dstA[1] = make_uint4(ad[4], ad[5], ad[6], ad[7]);
    }
    {
      const float* Bp = Bbase + (long)k0 * N;
#pragma unroll
      for (int jj = 0; jj < 4; jj++) {
        float v0 = Bp[(long)0 * N + 32 * jj];
        float v1 = Bp[(long)1 * N + 32 * jj];
        float v2 = Bp[(long)2 * N + 32 * jj];
        float v3 = Bp[(long)3 * N + 32 * jj];
        uint2 w;
        w.x = pack_bf16(v0, v1);
        w.y = pack_bf16(v2, v3);
        *(uint2*)&Bs[(bng + 32 * jj) * LDA + bkg] = w;
      }
    }
    __syncthreads();

    bf16x8 af[4], bfr[4];
#pragma unroll
    for (int i = 0; i < 4; i++)
      af[i] = *(const bf16x8*)&As[(wm + i * 16 + c) * LDA + q * 8];
#pragma unroll
    for (int j = 0; j < 4; j++)
      bfr[j] = *(const bf16x8*)&Bs[(wn + j * 16 + c) * LDA + q * 8];
#pragma unroll
    for (int i = 0; i < 4; i++)
#pragma unroll
      for (int j = 0; j < 4; j++)
        acc[i][j] = __builtin_amdgcn_mfma_f32_16x16x32_bf16(af[i], bfr[j], acc[i][j], 0, 0, 0);
  }

  if (SWIGLU) {
    unsigned short* H = (unsigned short*)Outall + e * sOut;
    const int ldh = N >> 1;
#pragma unroll
    for (int j = 0; j < 4; j++) {
      const int f = n0 + wn + j * 16 + c;
      const float bias = biasall[e * sBias + f];
#pragma unroll
      for (int i = 0; i < 4; i++) {
        const int rb = m0 + wm + i * 16 + q * 4;
#pragma unroll
        for (int r = 0; r < 4; r++) {
          float v = acc[i][j][r] + bias;
          float p = __shfl_xor(v, 1);
          float xg = (f & 1) ? p : v;
          float xl = (f & 1) ? v : p;
          xg = fminf(xg, 7.f);
          xl = fminf(fmaxf(xl, -7.f), 7.f);
          float sig = 1.f / (1.f + __expf(-1.702f * xg));
          float res = xg * sig * (xl + 1.f);
          if ((f & 1) == 0) {
            uint32_t ub = __builtin_bit_cast(uint32_t, res) + 0x8000u;
            H[(long)(rb + r) * ldh + (f >> 1)] = (unsigned short)(ub >> 16);
          }
        }
      }
    }
  } else {
    float* O = (float*)Outall + e * sOut;
#pragma unroll
    for (int j = 0; j < 4; j++) {
      const int col = n0 + wn + j * 16 + c;
      const float bias = biasall[e * sBias + col];
#pragma unroll
      for (int i = 0; i < 4; i++) {
        const int rb = m0 + wm + i * 16 + q * 4;
#pragma unroll
        for (int r = 0; r < 4; r++)
          O[(long)(rb + r) * N + col] = acc[i][j][r] + bias;
      }
    }
  }
}

extern "C" void kernel_launch(void* const* d_in, const int* in_sizes, int n_in,
                              void* d_out, int out_size, void* d_ws, size_t ws_size,
                              hipStream_t stream) {
  const float* x  = (const float*)d_in[0];   // (E,T,D) fp32
  const float* w1 = (const float*)d_in[1];   // (E,D,2D) fp32
  const float* b1 = (const float*)d_in[2];   // (E,2D)
  const float* w2 = (const float*)d_in[3];   // (E,D,D) fp32
  const float* b2 = (const float*)d_in[4];   // (E,D)
  float* out = (float*)d_out;                // (E,T,D) fp32

  const int E = 8, T = 2048, D = 2048;
  const size_t elems = (size_t)E * T * D;    // 33.5M
  const size_t need  = elems * 2 * 2;        // scratch(x16/w2t) + h = 128 MiB
  dim3 blk(256);

  if (ws_size >= need) {
    unsigned short* scratch = (unsigned short*)d_ws;   // x16, later reused for w2t
    unsigned short* h       = scratch + elems;         // bf16 intermediate (E,T,D)
    unsigned short* w1t     = (unsigned short*)d_out;  // borrow out buf: E*2D*D*2B == out_size

    // x -> bf16
    cvt_f32_bf16<<<dim3(2048), blk, 0, stream>>>(x, scratch, (long)(elems / 8));
    // w1 (D x 2D) -> w1t (2D x D) bf16, k-contiguous
    tcvt<<<dim3((2 * D) / 32, D / 64, E), blk, 0, stream>>>(
        w1, w1t, D, 2 * D, (long)D * 2 * D, (long)D * 2 * D);
    // GEMM1 + SwiGLU -> h (bf16)
    gemm_bf16<true><<<dim3((2 * D) / BN, T / BM, E), blk, 0, stream>>>(
        scratch, w1t, b1, h, T, 2 * D, D,
        (long)T * D, (long)2 * D * D, (long)2 * D, (long)T * D);
    // w2 (D x D) -> w2t (D x D)^T bf16 into scratch (x16 is dead now)
    tcvt<<<dim3(D / 32, D / 64, E), blk, 0, stream>>>(
        w2, scratch, D, D, (long)D * D, (long)D * D);
    // GEMM2 -> out fp32 (overwrites w1t, which is dead)
    gemm_bf16<false><<<dim3(D / BN, T / BM, E), blk, 0, stream>>>(
        h, scratch, b2, out, T, D, D,
        (long)T * D, (long)D * D, (long)D, (long)T * D);
  } else {
    // fallback: previous verified path (needs 64 MiB workspace)
    unsigned short* h = (unsigned short*)d_ws;
    gemm_fused<false, true><<<dim3((2 * D) / BN, T / BM, E), blk, 0, stream>>>(
        x, w1, b1, h, T, 2 * D, D,
        (long)T * D, (long)D * 2 * D, (long)2 * D, (long)T * D);
    gemm_fused<true, false><<<dim3(D / BN, T / BM, E), blk, 0, stream>>>(
        h, w2, b2, out, T, D, D,
        (long)T * D, (long)D * D, (long)D, (long)T * D);
  }
}